// Round 4
// baseline (43.320 us; speedup 1.0000x reference)
//
#include <hip/hip_runtime.h>

// Problem constants (B,S,D,M) = (8, 2048, 1024, 128), R = 257
#define SS 2048
#define DDIM 1024
#define D4 256          // DDIM / 4 (float4 columns)
#define BB 8
#define MM 128

__device__ __forceinline__ float4 f4zero() { return make_float4(0.f, 0.f, 0.f, 0.f); }
__device__ __forceinline__ float4 f4add(float4 a, float4 b) {
    return make_float4(a.x + b.x, a.y + b.y, a.z + b.z, a.w + b.w);
}
__device__ __forceinline__ float4 f4sub(float4 a, float4 b) {
    return make_float4(a.x - b.x, a.y - b.y, a.z - b.z, a.w - b.w);
}
__device__ __forceinline__ float4 f4mul(float4 a, float4 b) {
    return make_float4(a.x * b.x, a.y * b.y, a.z * b.z, a.w * b.w);
}
__device__ __forceinline__ float4 f4fma(float4 a, float4 b, float4 c) {
    return make_float4(fmaf(a.x, b.x, c.x), fmaf(a.y, b.y, c.y),
                       fmaf(a.z, b.z, c.z), fmaf(a.w, b.w, c.w));
}
__device__ __forceinline__ float4 f4fmas(float s, float4 b, float4 c) {
    return make_float4(fmaf(s, b.x, c.x), fmaf(s, b.y, c.y),
                       fmaf(s, b.z, c.z), fmaf(s, b.w, c.w));
}
__device__ __forceinline__ float4 f4scale(float4 a, float s) {
    return make_float4(a.x * s, a.y * s, a.z * s, a.w * s);
}
__device__ __forceinline__ float4 f4adds(float4 a, float s) {
    return make_float4(a.x + s, a.y + s, a.z + s, a.w + s);
}

// ---------------------------------------------------------------------------
// k_part: partial sums of table rows. Group g covers rows r in [8g+1, 8g+8].
// part[g][d4] = sum of those 8 rows. 32 groups cover r = 1..256.
// ---------------------------------------------------------------------------
__global__ __launch_bounds__(256) void k_part(const float4* __restrict__ tbl4,
                                              float4* __restrict__ part) {
    const int g = blockIdx.x;      // 0..31
    const int tid = threadIdx.x;   // 0..255 (float4 column)
    float4 acc = f4zero();
    const int r0 = g * 8 + 1;
#pragma unroll
    for (int j = 0; j < 8; ++j)
        acc = f4add(acc, tbl4[(r0 + j) * D4 + tid]);
    part[g * D4 + tid] = acc;
}

// ---------------------------------------------------------------------------
// k_scan: Pre[r][d] = sum_{r'=1..r} table[r'][d], r = 0..255 (Pre[0] = 0).
// Block g: base = sum of part[g'<g], then walks its 8 rows.
// ---------------------------------------------------------------------------
__global__ __launch_bounds__(256) void k_scan(const float4* __restrict__ tbl4,
                                              const float4* __restrict__ part,
                                              float4* __restrict__ pre) {
    const int g = blockIdx.x;      // 0..31
    const int tid = threadIdx.x;
    float4 acc = f4zero();
    for (int gp = 0; gp < g; ++gp)
        acc = f4add(acc, part[gp * D4 + tid]);
    if (g == 0) pre[tid] = f4zero();   // Pre[0] = 0
    const int r0 = g * 8 + 1;
#pragma unroll
    for (int j = 0; j < 8; ++j) {
        const int r = r0 + j;
        acc = f4add(acc, tbl4[r * D4 + tid]);
        if (r <= 255) pre[r * D4 + tid] = acc;   // r=256 (g=31,j=7) not needed
    }
}

// ---------------------------------------------------------------------------
// k_main: out[b,i,d] = (w0*x[b,i-1] + (w1+S-1)*x[b,i] + w2*x[b,i+1] + pos(i,d)) / S
// pos(i,d) = bias + (w1-1)*T[M] + [i>=1]w0*T[M-1] + [i<=S-2]w2*T[M+1]
//          + cl(i)*T[0] + ch(i)*T[2M] + Pre[hi(i)] - Pre[lo(i)-1]
// Interior i in [127,1920]: cl=1920-i, ch=i-127, Pre-diff = PreFull (const)
//   -> pos = K0 + i*(T[2M]-T[0]), fully hoisted.
// Block = (batch, 16-row strip). Thread = 4 consecutive d. x rolls in regs.
// ---------------------------------------------------------------------------
__global__ __launch_bounds__(256) void k_main(const float4* __restrict__ x4,
                                              const float4* __restrict__ tbl4,
                                              const float* __restrict__ w,
                                              const float4* __restrict__ bias4,
                                              const float4* __restrict__ pre4,
                                              float4* __restrict__ out4) {
    const int tid = threadIdx.x;          // d4
    const int bid = blockIdx.x;           // b*128 + strip
    const int strip = bid & 127;
    const int b = bid >> 7;
    const int i0 = strip << 4;

    // hoisted per-d constants (all L1/L2-hot)
    const float4 T0  = tbl4[0 * D4 + tid];
    const float4 T2M = tbl4[256 * D4 + tid];
    const float4 Tm  = tbl4[128 * D4 + tid];
    const float4 Tmm = tbl4[127 * D4 + tid];
    const float4 Tmp = tbl4[129 * D4 + tid];
    const float4 bs  = bias4[tid];

    // w is (D,3) row-major; 3 float4s cover w for our 4 d's -> unscramble
    const float4* w4 = (const float4*)w;
    const float4 q0 = w4[3 * tid + 0];
    const float4 q1 = w4[3 * tid + 1];
    const float4 q2 = w4[3 * tid + 2];
    const float4 w0 = make_float4(q0.x, q0.w, q1.z, q2.y);
    const float4 w1 = make_float4(q0.y, q1.x, q1.w, q2.z);
    const float4 w2 = make_float4(q0.z, q1.y, q2.x, q2.w);
    const float4 w1s = f4adds(w1, (float)(SS - 1));
    const float invS = 1.0f / (float)SS;

    const float4* xr = x4 + (b * SS + i0) * D4 + tid;
    float4* orow = out4 + (b * SS + i0) * D4 + tid;

    if (strip >= 8 && strip <= 119) {
        // ------- interior path: i in [128, 1919] -------
        const float4 PF = pre4[255 * D4 + tid];
        float4 K0 = bs;
        K0 = f4fma(f4adds(w1, -1.f), Tm, K0);
        K0 = f4fma(w0, Tmm, K0);
        K0 = f4fma(w2, Tmp, K0);
        K0 = f4fmas(1920.f, T0, K0);
        K0 = f4fmas(-127.f, T2M, K0);
        K0 = f4add(K0, PF);
        const float4 Kc = f4sub(T2M, T0);

        float4 xm = xr[-D4];        // i0-1 >= 127: safe
        float4 x0 = xr[0];
#pragma unroll
        for (int j = 0; j < 16; ++j) {
            const float4 xp = xr[(j + 1) * D4];   // i0+16 <= 1920: safe
            const float fi = (float)(i0 + j);
            float4 acc = f4fmas(fi, Kc, K0);
            acc = f4fma(w0, xm, acc);
            acc = f4fma(w1s, x0, acc);
            acc = f4fma(w2, xp, acc);
            orow[j * D4] = f4scale(acc, invS);
            xm = x0; x0 = xp;
        }
    } else {
        // ------- edge path: general formula, per-i Pre lookups (L2-hot) -------
        float4 K0e = bs;
        K0e = f4fma(f4adds(w1, -1.f), Tm, K0e);
        const float4 w0Tmm = f4mul(w0, Tmm);
        const float4 w2Tmp = f4mul(w2, Tmp);

        float4 xm = (i0 == 0) ? f4zero() : xr[-D4];
        float4 x0 = xr[0];
#pragma unroll
        for (int j = 0; j < 16; ++j) {
            const int i = i0 + j;
            const float4 xp = (i < SS - 1) ? xr[(j + 1) * D4] : f4zero();
            const int cl = max(0, 1920 - i);          // count of clipped -M (T[0])
            const int ch = max(0, i - 127);           // count of clipped +M (T[2M])
            const int hi = min(i + 128, 255);
            const int lom1 = max(i - 1920, 0);        // lo - 1
            const float4 ph = pre4[hi * D4 + tid];
            const float4 pl = pre4[lom1 * D4 + tid];
            float4 pos = f4add(K0e, f4sub(ph, pl));
            pos = f4fmas((float)cl, T0, pos);
            pos = f4fmas((float)ch, T2M, pos);
            if (i >= 1)      pos = f4add(pos, w0Tmm);
            if (i <= SS - 2) pos = f4add(pos, w2Tmp);
            float4 acc = f4fma(w0, xm, pos);
            acc = f4fma(w1s, x0, acc);
            acc = f4fma(w2, xp, acc);
            orow[j * D4] = f4scale(acc, invS);
            xm = x0; x0 = xp;
        }
    }
}

extern "C" void kernel_launch(void* const* d_in, const int* in_sizes, int n_in,
                              void* d_out, int out_size, void* d_ws, size_t ws_size,
                              hipStream_t stream) {
    const float* x     = (const float*)d_in[0];   // (B,S,D)
    const float* table = (const float*)d_in[1];   // (R,D) = (257,1024)
    const float* w     = (const float*)d_in[2];   // (D,3)
    const float* bias  = (const float*)d_in[3];   // (D,)
    float* out = (float*)d_out;

    // ws layout: Pre[256][1024] floats (1 MiB), then Part[32][1024] floats (128 KiB)
    float* pre  = (float*)d_ws;
    float* part = pre + 256 * DDIM;

    k_part<<<32, 256, 0, stream>>>((const float4*)table, (float4*)part);
    k_scan<<<32, 256, 0, stream>>>((const float4*)table, (const float4*)part,
                                   (float4*)pre);
    k_main<<<BB * (SS / 16), 256, 0, stream>>>((const float4*)x,
                                               (const float4*)table, w,
                                               (const float4*)bias,
                                               (const float4*)pre,
                                               (float4*)out);
}